// Round 6
// baseline (182.469 us; speedup 1.0000x reference)
//
#include <hip/hip_runtime.h>

// GCNConv + residual + ReLU, fp32 in/out — single-pass binning + bf16 gather.
//   x  [N,64]  d_in[0]  float
//   W  [64,64] d_in[1]  float   (h = x @ W^T)
//   b  [64]    d_in[2]  float
//   ei [2,E]   d_in[3]  int32   (src = ei[0..E), dst = ei[E..2E))
// out [N,64] float
//
// h'[s][:] = bf16( dinv[s] * (x @ W^T)[s][:] )   (12.8 MB, gather-friendly)
// out[i]   = relu( dinv[i] * (h'[i] + sum_{s->i} h'[s]) + b + x[i] )
//
// R12 — PADDED ATOMIC COUNTERS. R11 surfaced fill directly: 55.7 us,
// 11% HBM, 0.3% VALU, 23.8% occ -> pure atomic serialization. R6's
// XCD-partitioned variant (one XCD per cur line) ran 35 us with identical
// atomics -> cross-XCD SAME-LINE contention is the mechanism: 32 counters
// per 128B TCC line x deg 8 = ~256 atomics/line from 8 XCDs, serialized
// per-line. Fix: 128B stride per counter (cur[d<<5], 12.8 MB, memset ~2us).
// Per-line atomics drop 256 -> 8. Prediction: fill 55.7 -> 15-25 us,
// total ~140 us. deg reads in linear/gather become strided (+~2us BW).

#define NN 100000
#define NE 800000
#define DD 64
#define CAP 32
#define CSTR 5   // log2(counter stride in ints): 32 ints = 128 B per counter

typedef unsigned int uint;
typedef unsigned short ushort;

__device__ __forceinline__ ushort f2bf(float f) {
    uint u = __float_as_uint(f);
    u += 0x7fffu + ((u >> 16) & 1u);   // round-to-nearest-even
    return (ushort)(u >> 16);
}
__device__ __forceinline__ float bflo(uint u) { return __uint_as_float(u << 16); }
__device__ __forceinline__ float bfhi(uint u) { return __uint_as_float(u & 0xffff0000u); }

// Single-pass bin fill: padded cursor doubles as degree. All 64 lanes
// active; per-thread 4 edges (coalesced int4 src + dst loads), 4
// independent atomicAdds (each counter on its own 128B line), then the
// dependent slot stores.
__global__ __launch_bounds__(256) void fill_kernel(const int* __restrict__ ei,
                                                   int* __restrict__ cur,
                                                   int* __restrict__ srcIdx) {
    int base = (blockIdx.x * 256 + threadIdx.x) * 4;
    if (base >= NE) return;
    // NE % 4 == 0, so base<NE implies base+3<NE: full int4 loads are safe.
    int4 sv = *(const int4*)(ei + base);        // 4 srcs
    int4 dv = *(const int4*)(ei + NE + base);   // 4 dsts
    int c0 = atomicAdd(&cur[dv.x << CSTR], 1);
    int c1 = atomicAdd(&cur[dv.y << CSTR], 1);
    int c2 = atomicAdd(&cur[dv.z << CSTR], 1);
    int c3 = atomicAdd(&cur[dv.w << CSTR], 1);
    if (c0 < CAP) srcIdx[(dv.x << 5) + c0] = sv.x;
    if (c1 < CAP) srcIdx[(dv.y << 5) + c1] = sv.y;
    if (c2 < CAP) srcIdx[(dv.z << 5) + c2] = sv.z;
    if (c3 < CAP) srcIdx[(dv.w << 5) + c3] = sv.w;
}

// linear: h' = bf16(rsqrt(deg+1) * (x @ W^T)).
// Block = 256 thr, tile 64 rows x 64 cols; thread = 4 contiguous rows x 4 cols.
// kq-loop capped at unroll 2 (full unroll spilled in R4: VGPR=256, scratch).
__global__ __launch_bounds__(256) void linear_kernel(const float4* __restrict__ x4g,
                                                     const float* __restrict__ W,
                                                     const int* __restrict__ deg,
                                                     ushort4* __restrict__ hq4) {
    __shared__ float4 wt4[64 * 16];   // 16 KB: wt4[k*16 + c4] = W^T[k][4c4..4c4+3]
    __shared__ float4 xs4[64 * 17];   // 17.4 KB, row-stride 17 float4
    int t = threadIdx.x;

    float* wt = (float*)wt4;
    for (int m = t; m < 4096; m += 256)            // wt[k*64+j] = W[j*64+k]
        wt[m] = W[(m & 63) * 64 + (m >> 6)];       // LDS write contiguous: clean

    int rowBase = blockIdx.x * 64;
    for (int m = t; m < 1024; m += 256) {
        int rl = m >> 4;
        xs4[rl * 17 + (m & 15)] = (rowBase + rl < NN)
            ? x4g[(size_t)rowBase * 16 + m]
            : make_float4(0.f, 0.f, 0.f, 0.f);
    }
    __syncthreads();

    int tc = t & 15;   // col-quad: cols tc*4..tc*4+3
    int tr = t >> 4;   // rows tr*4 .. tr*4+3
    float4 acc[4];
#pragma unroll
    for (int i = 0; i < 4; ++i) acc[i] = make_float4(0.f, 0.f, 0.f, 0.f);

#pragma unroll 2
    for (int kq = 0; kq < 16; ++kq) {
        float4 w0 = wt4[(kq * 4 + 0) * 16 + tc];
        float4 w1 = wt4[(kq * 4 + 1) * 16 + tc];
        float4 w2 = wt4[(kq * 4 + 2) * 16 + tc];
        float4 w3 = wt4[(kq * 4 + 3) * 16 + tc];
#pragma unroll
        for (int i = 0; i < 4; ++i) {
            float4 xv = xs4[(tr * 4 + i) * 17 + kq];
            acc[i].x += xv.x * w0.x + xv.y * w1.x + xv.z * w2.x + xv.w * w3.x;
            acc[i].y += xv.x * w0.y + xv.y * w1.y + xv.z * w2.y + xv.w * w3.y;
            acc[i].z += xv.x * w0.z + xv.y * w1.z + xv.z * w2.z + xv.w * w3.z;
            acc[i].w += xv.x * w0.w + xv.y * w1.w + xv.z * w2.w + xv.w * w3.w;
        }
    }

#pragma unroll
    for (int i = 0; i < 4; ++i) {
        int g = rowBase + tr * 4 + i;
        if (g < NN) {
            float sc = rsqrtf((float)deg[g << CSTR] + 1.0f);
            ushort4 o;
            o.x = f2bf(acc[i].x * sc); o.y = f2bf(acc[i].y * sc);
            o.z = f2bf(acc[i].z * sc); o.w = f2bf(acc[i].w * sc);
            hq4[(size_t)g * 16 + tc] = o;
        }
    }
}

// gather: 8 lanes per node, lane covers 8 columns (one uint4 = 8 bf16 per load).
// Bin region is node-major: slots node*32 .. node*32+deg-1.
// Lane l prefetches bin slots 4l..4l+3 as ONE int4 (8 lanes cover the whole
// 128B bin, coalesced). Edge indices __shfl-broadcast; each 8-edge group
// issues up to 8 independent exec-predicated hq row loads (zero-init, bf
// decode of 0 is +0.0f). Self-loop, bias, residual, ReLU fused.
__global__ __launch_bounds__(256) void gather_kernel(const int* __restrict__ srcIdx,
                                                     const int* __restrict__ deg,
                                                     const uint4* __restrict__ hq4,
                                                     const float4* __restrict__ x4,
                                                     const float* __restrict__ b,
                                                     float4* __restrict__ out4) {
    int t = blockIdx.x * blockDim.x + threadIdx.x;
    int node = t >> 3;        // 32 nodes per block
    int l = t & 7;            // lane covers columns l*8 .. l*8+7
    if (node >= NN) return;

    int dg = deg[node << CSTR];
    float di = rsqrtf((float)dg + 1.0f);
    if (dg > CAP) dg = CAP;   // astronomically unlikely; avoids unwritten slots

    // All independent loads up front: self row, my 4 bin slots, residual x.
    uint4 vs = hq4[(size_t)node * 8 + l];                      // self (pre-scaled)
    int4  u  = ((const int4*)srcIdx)[node * 8 + l];            // bin slots 4l..4l+3
    float4 xa = x4[(size_t)node * 16 + l * 2];
    float4 xb = x4[(size_t)node * 16 + l * 2 + 1];

    float acc[8];
    acc[0] = bflo(vs.x); acc[1] = bfhi(vs.x);
    acc[2] = bflo(vs.y); acc[3] = bfhi(vs.y);
    acc[4] = bflo(vs.z); acc[5] = bfhi(vs.z);
    acc[6] = bflo(vs.w); acc[7] = bfhi(vs.w);

    int base = (threadIdx.x & 63) & ~7;   // wave-local lane 0 of this node's group

#define ACC8(v)                                        \
    acc[0] += bflo((v).x); acc[1] += bfhi((v).x);      \
    acc[2] += bflo((v).y); acc[3] += bfhi((v).y);      \
    acc[4] += bflo((v).z); acc[5] += bfhi((v).z);      \
    acc[6] += bflo((v).w); acc[7] += bfhi((v).w);

#define GROUP(GI)                                                              \
    {                                                                          \
        int la = base + 2 * (GI), lb = la + 1, eb = (GI) * 8;                  \
        int s0 = __shfl(u.x, la, 64), s1 = __shfl(u.y, la, 64);                \
        int s2 = __shfl(u.z, la, 64), s3 = __shfl(u.w, la, 64);                \
        int s4 = __shfl(u.x, lb, 64), s5 = __shfl(u.y, lb, 64);                \
        int s6 = __shfl(u.z, lb, 64), s7 = __shfl(u.w, lb, 64);                \
        uint4 z = make_uint4(0u, 0u, 0u, 0u);                                  \
        uint4 v0 = z, v1 = z, v2 = z, v3 = z, v4 = z, v5 = z, v6 = z, v7 = z;  \
        if (eb + 0 < dg) v0 = hq4[(size_t)s0 * 8 + l];                         \
        if (eb + 1 < dg) v1 = hq4[(size_t)s1 * 8 + l];                         \
        if (eb + 2 < dg) v2 = hq4[(size_t)s2 * 8 + l];                         \
        if (eb + 3 < dg) v3 = hq4[(size_t)s3 * 8 + l];                         \
        if (eb + 4 < dg) v4 = hq4[(size_t)s4 * 8 + l];                         \
        if (eb + 5 < dg) v5 = hq4[(size_t)s5 * 8 + l];                         \
        if (eb + 6 < dg) v6 = hq4[(size_t)s6 * 8 + l];                         \
        if (eb + 7 < dg) v7 = hq4[(size_t)s7 * 8 + l];                         \
        ACC8(v0); ACC8(v1); ACC8(v2); ACC8(v3);                                \
        ACC8(v4); ACC8(v5); ACC8(v6); ACC8(v7);                                \
    }

    GROUP(0)
    if (dg > 8)  GROUP(1)
    if (dg > 16) GROUP(2)
    if (dg > 24) GROUP(3)

#undef GROUP
#undef ACC8

    float4 oa, ob;
    int cb = l * 8;
    oa.x = fmaxf(di * acc[0] + b[cb + 0] + xa.x, 0.f);
    oa.y = fmaxf(di * acc[1] + b[cb + 1] + xa.y, 0.f);
    oa.z = fmaxf(di * acc[2] + b[cb + 2] + xa.z, 0.f);
    oa.w = fmaxf(di * acc[3] + b[cb + 3] + xa.w, 0.f);
    ob.x = fmaxf(di * acc[4] + b[cb + 4] + xb.x, 0.f);
    ob.y = fmaxf(di * acc[5] + b[cb + 5] + xb.y, 0.f);
    ob.z = fmaxf(di * acc[6] + b[cb + 6] + xb.z, 0.f);
    ob.w = fmaxf(di * acc[7] + b[cb + 7] + xb.w, 0.f);
    out4[(size_t)node * 16 + l * 2]     = oa;
    out4[(size_t)node * 16 + l * 2 + 1] = ob;
}

extern "C" void kernel_launch(void* const* d_in, const int* in_sizes, int n_in,
                              void* d_out, int out_size, void* d_ws, size_t ws_size,
                              hipStream_t stream) {
    const float* x = (const float*)d_in[0];
    const float* W = (const float*)d_in[1];
    const float* b = (const float*)d_in[2];
    const int* ei = (const int*)d_in[3];

    char* ws = (char*)d_ws;
    int*    cur    = (int*)(ws + 0);           // 12,800,000 B (stride-32 padded counters)
    int*    srcIdx = (int*)(ws + 12800000);    // 12,800,000 B (node-major 32-slot bins)
    ushort* hq     = (ushort*)(ws + 25600000); // 12,800,000 B

    hipMemsetAsync(cur, 0, (size_t)NN * 32 * sizeof(int), stream);

    fill_kernel<<<(NE / 4 + 255) / 256, 256, 0, stream>>>(ei, cur, srcIdx);
    linear_kernel<<<(NN + 63) / 64, 256, 0, stream>>>((const float4*)x, W, cur,
                                                      (ushort4*)hq);
    gather_kernel<<<NN / 32, 256, 0, stream>>>(srcIdx, cur, (const uint4*)hq,
                                               (const float4*)x, b, (float4*)d_out);
}

// Round 7
// 169.314 us; speedup vs baseline: 1.0777x; 1.0777x over previous
//
#include <hip/hip_runtime.h>

// GCNConv + residual + ReLU, fp32 in/out — routed XCD-local binning + bf16 gather.
//   x  [N,64]  d_in[0]  float
//   W  [64,64] d_in[1]  float   (h = x @ W^T)
//   b  [64]    d_in[2]  float
//   ei [2,E]   d_in[3]  int32   (src = ei[0..E), dst = ei[E..2E))
// out [N,64] float
//
// h'[s][:] = bf16( dinv[s] * (x @ W^T)[s][:] )   (12.8 MB, gather-friendly)
// out[i]   = relu( dinv[i] * (h'[i] + sum_{s->i} h'[s]) + b + x[i] )
//
// R13 — ROUTED FILL. Evidence: R6 (dst&7-partitioned, 35us) vs R11/R12
// (all-XCD, 55.7/56.3us; counter padding = NO effect). Discriminator is
// srcIdx BIN-LINE ownership: a node's bin is one 128B line; written from
// 8 XCDs it ping-pongs through the coherence point (0.3% VALU, 47.6 MB
// partial-line writeback). Fix without R6's 8x-read/masked-lane waste:
//   pass 1 route_kernel: read edges once, LDS-rank by dst&7 into 8
//     per-block contiguous runs (single-writer lines).
//   pass 2 place_kernel: g = blockIdx&7 (round-robin -> one XCD per g)
//     consumes group-g runs; atomics + bin stores are XCD-local.
// Pre-committed read: place <=20us -> theory confirmed; ~35us -> returning-
// atomic rate is the wall (next: LDS-windowed binning); >=45us -> revert R6.

#define NN 100000
#define NE 800000
#define DD 64
#define CAP 32
#define NBLK 782      // ceil(NE / 1024) edge-blocks of 1024 edges
#define RCAP 512      // per (group,block) run capacity; mean 128, >22 sigma

typedef unsigned int uint;
typedef unsigned short ushort;

__device__ __forceinline__ ushort f2bf(float f) {
    uint u = __float_as_uint(f);
    u += 0x7fffu + ((u >> 16) & 1u);   // round-to-nearest-even
    return (ushort)(u >> 16);
}
__device__ __forceinline__ float bflo(uint u) { return __uint_as_float(u << 16); }
__device__ __forceinline__ float bfhi(uint u) { return __uint_as_float(u & 0xffff0000u); }

// Pass 1: route edges into 8 dst-group runs per block. One coalesced read
// of the edge list; rank via LDS atomics; runs are 4KB contiguous,
// single-writer (no cross-XCD line sharing anywhere).
__global__ __launch_bounds__(256) void route_kernel(const int* __restrict__ ei,
                                                    int2* __restrict__ route,
                                                    int* __restrict__ counts) {
    __shared__ int lcnt[8];
    int t = threadIdx.x;
    if (t < 8) lcnt[t] = 0;
    __syncthreads();

    int blk = blockIdx.x;
    int base = blk * 1024 + t * 4;
    int4 sv, dv;
    int gg[4], rk[4];
    bool valid = base < NE;   // NE%4==0: valid => full int4 safe
    if (valid) {
        sv = *(const int4*)(ei + base);
        dv = *(const int4*)(ei + NE + base);
        gg[0] = dv.x & 7; gg[1] = dv.y & 7; gg[2] = dv.z & 7; gg[3] = dv.w & 7;
        rk[0] = atomicAdd(&lcnt[gg[0]], 1);
        rk[1] = atomicAdd(&lcnt[gg[1]], 1);
        rk[2] = atomicAdd(&lcnt[gg[2]], 1);
        rk[3] = atomicAdd(&lcnt[gg[3]], 1);
        int s[4] = {sv.x, sv.y, sv.z, sv.w};
        int d[4] = {dv.x, dv.y, dv.z, dv.w};
#pragma unroll
        for (int j = 0; j < 4; ++j) {
            if (rk[j] < RCAP)   // p(overflow) ~ 1e-100; mirrors CAP guard
                route[((size_t)(gg[j] * NBLK + blk) << 9) + rk[j]] =
                    make_int2(s[j], d[j]);
        }
    }
    __syncthreads();
    if (t < 8) counts[blk * 8 + t] = lcnt[t] < RCAP ? lcnt[t] : RCAP;
}

// Pass 2: g = blockIdx&7 -> with round-robin block->XCD dispatch, all
// group-g blocks land on one XCD; every cur/srcIdx bin line of group g
// is touched by that XCD only. All lanes active, edges read once.
__global__ __launch_bounds__(256) void place_kernel(const int2* __restrict__ route,
                                                    const int* __restrict__ counts,
                                                    int* __restrict__ cur,
                                                    int* __restrict__ srcIdx) {
    int g = blockIdx.x & 7;
    int blk = blockIdx.x >> 3;
    int cnt = counts[blk * 8 + g];
    const int2* run = route + ((size_t)(g * NBLK + blk) << 9);
    for (int i = threadIdx.x; i < cnt; i += 256) {
        int2 e = run[i];
        int c = atomicAdd(&cur[e.y], 1);
        if (c < CAP) srcIdx[(e.y << 5) + c] = e.x;
    }
}

// Fallback single-pass fill (only if ws too small for route buffers).
__global__ __launch_bounds__(256) void fill_kernel(const int* __restrict__ ei,
                                                   int* __restrict__ cur,
                                                   int* __restrict__ srcIdx) {
    int base = (blockIdx.x * 256 + threadIdx.x) * 4;
    if (base >= NE) return;
    int4 sv = *(const int4*)(ei + base);
    int4 dv = *(const int4*)(ei + NE + base);
    int c0 = atomicAdd(&cur[dv.x], 1);
    int c1 = atomicAdd(&cur[dv.y], 1);
    int c2 = atomicAdd(&cur[dv.z], 1);
    int c3 = atomicAdd(&cur[dv.w], 1);
    if (c0 < CAP) srcIdx[(dv.x << 5) + c0] = sv.x;
    if (c1 < CAP) srcIdx[(dv.y << 5) + c1] = sv.y;
    if (c2 < CAP) srcIdx[(dv.z << 5) + c2] = sv.z;
    if (c3 < CAP) srcIdx[(dv.w << 5) + c3] = sv.w;
}

// linear: h' = bf16(rsqrt(deg+1) * (x @ W^T)).
// Block = 256 thr, tile 64 rows x 64 cols; thread = 4 contiguous rows x 4 cols.
// kq-loop capped at unroll 2 (full unroll spilled in R4: VGPR=256, scratch).
__global__ __launch_bounds__(256) void linear_kernel(const float4* __restrict__ x4g,
                                                     const float* __restrict__ W,
                                                     const int* __restrict__ deg,
                                                     ushort4* __restrict__ hq4) {
    __shared__ float4 wt4[64 * 16];   // 16 KB: wt4[k*16 + c4] = W^T[k][4c4..4c4+3]
    __shared__ float4 xs4[64 * 17];   // 17.4 KB, row-stride 17 float4
    int t = threadIdx.x;

    float* wt = (float*)wt4;
    for (int m = t; m < 4096; m += 256)            // wt[k*64+j] = W[j*64+k]
        wt[m] = W[(m & 63) * 64 + (m >> 6)];       // LDS write contiguous: clean

    int rowBase = blockIdx.x * 64;
    for (int m = t; m < 1024; m += 256) {
        int rl = m >> 4;
        xs4[rl * 17 + (m & 15)] = (rowBase + rl < NN)
            ? x4g[(size_t)rowBase * 16 + m]
            : make_float4(0.f, 0.f, 0.f, 0.f);
    }
    __syncthreads();

    int tc = t & 15;   // col-quad: cols tc*4..tc*4+3
    int tr = t >> 4;   // rows tr*4 .. tr*4+3
    float4 acc[4];
#pragma unroll
    for (int i = 0; i < 4; ++i) acc[i] = make_float4(0.f, 0.f, 0.f, 0.f);

#pragma unroll 2
    for (int kq = 0; kq < 16; ++kq) {
        float4 w0 = wt4[(kq * 4 + 0) * 16 + tc];
        float4 w1 = wt4[(kq * 4 + 1) * 16 + tc];
        float4 w2 = wt4[(kq * 4 + 2) * 16 + tc];
        float4 w3 = wt4[(kq * 4 + 3) * 16 + tc];
#pragma unroll
        for (int i = 0; i < 4; ++i) {
            float4 xv = xs4[(tr * 4 + i) * 17 + kq];
            acc[i].x += xv.x * w0.x + xv.y * w1.x + xv.z * w2.x + xv.w * w3.x;
            acc[i].y += xv.x * w0.y + xv.y * w1.y + xv.z * w2.y + xv.w * w3.y;
            acc[i].z += xv.x * w0.z + xv.y * w1.z + xv.z * w2.z + xv.w * w3.z;
            acc[i].w += xv.x * w0.w + xv.y * w1.w + xv.z * w2.w + xv.w * w3.w;
        }
    }

#pragma unroll
    for (int i = 0; i < 4; ++i) {
        int g = rowBase + tr * 4 + i;
        if (g < NN) {
            float sc = rsqrtf((float)deg[g] + 1.0f);
            ushort4 o;
            o.x = f2bf(acc[i].x * sc); o.y = f2bf(acc[i].y * sc);
            o.z = f2bf(acc[i].z * sc); o.w = f2bf(acc[i].w * sc);
            hq4[(size_t)g * 16 + tc] = o;
        }
    }
}

// gather: 8 lanes per node, lane covers 8 columns (one uint4 = 8 bf16 per load).
// Bin region is node-major: slots node*32 .. node*32+deg-1.
// Lane l prefetches bin slots 4l..4l+3 as ONE int4 (8 lanes cover the whole
// 128B bin, coalesced). Edge indices __shfl-broadcast; each 8-edge group
// issues up to 8 independent exec-predicated hq row loads (zero-init, bf
// decode of 0 is +0.0f). Self-loop, bias, residual, ReLU fused.
__global__ __launch_bounds__(256) void gather_kernel(const int* __restrict__ srcIdx,
                                                     const int* __restrict__ deg,
                                                     const uint4* __restrict__ hq4,
                                                     const float4* __restrict__ x4,
                                                     const float* __restrict__ b,
                                                     float4* __restrict__ out4) {
    int t = blockIdx.x * blockDim.x + threadIdx.x;
    int node = t >> 3;        // 32 nodes per block
    int l = t & 7;            // lane covers columns l*8 .. l*8+7
    if (node >= NN) return;

    int dg = deg[node];
    float di = rsqrtf((float)dg + 1.0f);
    if (dg > CAP) dg = CAP;   // astronomically unlikely; avoids unwritten slots

    // All independent loads up front: self row, my 4 bin slots, residual x.
    uint4 vs = hq4[(size_t)node * 8 + l];                      // self (pre-scaled)
    int4  u  = ((const int4*)srcIdx)[node * 8 + l];            // bin slots 4l..4l+3
    float4 xa = x4[(size_t)node * 16 + l * 2];
    float4 xb = x4[(size_t)node * 16 + l * 2 + 1];

    float acc[8];
    acc[0] = bflo(vs.x); acc[1] = bfhi(vs.x);
    acc[2] = bflo(vs.y); acc[3] = bfhi(vs.y);
    acc[4] = bflo(vs.z); acc[5] = bfhi(vs.z);
    acc[6] = bflo(vs.w); acc[7] = bfhi(vs.w);

    int base = (threadIdx.x & 63) & ~7;   // wave-local lane 0 of this node's group

#define ACC8(v)                                        \
    acc[0] += bflo((v).x); acc[1] += bfhi((v).x);      \
    acc[2] += bflo((v).y); acc[3] += bfhi((v).y);      \
    acc[4] += bflo((v).z); acc[5] += bfhi((v).z);      \
    acc[6] += bflo((v).w); acc[7] += bfhi((v).w);

#define GROUP(GI)                                                              \
    {                                                                          \
        int la = base + 2 * (GI), lb = la + 1, eb = (GI) * 8;                  \
        int s0 = __shfl(u.x, la, 64), s1 = __shfl(u.y, la, 64);                \
        int s2 = __shfl(u.z, la, 64), s3 = __shfl(u.w, la, 64);                \
        int s4 = __shfl(u.x, lb, 64), s5 = __shfl(u.y, lb, 64);                \
        int s6 = __shfl(u.z, lb, 64), s7 = __shfl(u.w, lb, 64);                \
        uint4 z = make_uint4(0u, 0u, 0u, 0u);                                  \
        uint4 v0 = z, v1 = z, v2 = z, v3 = z, v4 = z, v5 = z, v6 = z, v7 = z;  \
        if (eb + 0 < dg) v0 = hq4[(size_t)s0 * 8 + l];                         \
        if (eb + 1 < dg) v1 = hq4[(size_t)s1 * 8 + l];                         \
        if (eb + 2 < dg) v2 = hq4[(size_t)s2 * 8 + l];                         \
        if (eb + 3 < dg) v3 = hq4[(size_t)s3 * 8 + l];                         \
        if (eb + 4 < dg) v4 = hq4[(size_t)s4 * 8 + l];                         \
        if (eb + 5 < dg) v5 = hq4[(size_t)s5 * 8 + l];                         \
        if (eb + 6 < dg) v6 = hq4[(size_t)s6 * 8 + l];                         \
        if (eb + 7 < dg) v7 = hq4[(size_t)s7 * 8 + l];                         \
        ACC8(v0); ACC8(v1); ACC8(v2); ACC8(v3);                                \
        ACC8(v4); ACC8(v5); ACC8(v6); ACC8(v7);                                \
    }

    GROUP(0)
    if (dg > 8)  GROUP(1)
    if (dg > 16) GROUP(2)
    if (dg > 24) GROUP(3)

#undef GROUP
#undef ACC8

    float4 oa, ob;
    int cb = l * 8;
    oa.x = fmaxf(di * acc[0] + b[cb + 0] + xa.x, 0.f);
    oa.y = fmaxf(di * acc[1] + b[cb + 1] + xa.y, 0.f);
    oa.z = fmaxf(di * acc[2] + b[cb + 2] + xa.z, 0.f);
    oa.w = fmaxf(di * acc[3] + b[cb + 3] + xa.w, 0.f);
    ob.x = fmaxf(di * acc[4] + b[cb + 4] + xb.x, 0.f);
    ob.y = fmaxf(di * acc[5] + b[cb + 5] + xb.y, 0.f);
    ob.z = fmaxf(di * acc[6] + b[cb + 6] + xb.z, 0.f);
    ob.w = fmaxf(di * acc[7] + b[cb + 7] + xb.w, 0.f);
    out4[(size_t)node * 16 + l * 2]     = oa;
    out4[(size_t)node * 16 + l * 2 + 1] = ob;
}

extern "C" void kernel_launch(void* const* d_in, const int* in_sizes, int n_in,
                              void* d_out, int out_size, void* d_ws, size_t ws_size,
                              hipStream_t stream) {
    const float* x = (const float*)d_in[0];
    const float* W = (const float*)d_in[1];
    const float* b = (const float*)d_in[2];
    const int* ei = (const int*)d_in[3];

    char* ws = (char*)d_ws;
    int*    cur    = (int*)(ws + 0);           //    400,000 B (doubles as deg)
    int*    srcIdx = (int*)(ws + 400000);      // 12,800,000 B (node-major 32-slot bins)
    ushort* hq     = (ushort*)(ws + 13200000); // 12,800,000 B
    int2*   route  = (int2*)(ws + 26000000);   // 25,624,576 B (8*NBLK runs of RCAP)
    int*    counts = (int*)(ws + 51624576);    //     25,024 B [blk][8]
    const size_t WS_NEED = 51649600;

    hipMemsetAsync(cur, 0, NN * sizeof(int), stream);

    if (ws_size >= WS_NEED) {
        route_kernel<<<NBLK, 256, 0, stream>>>(ei, route, counts);
        place_kernel<<<NBLK * 8, 256, 0, stream>>>(route, counts, cur, srcIdx);
    } else {
        fill_kernel<<<(NE / 4 + 255) / 256, 256, 0, stream>>>(ei, cur, srcIdx);
    }
    linear_kernel<<<(NN + 63) / 64, 256, 0, stream>>>((const float4*)x, W, cur,
                                                      (ushort4*)hq);
    gather_kernel<<<NN / 32, 256, 0, stream>>>(srcIdx, cur, (const uint4*)hq,
                                               (const float4*)x, b, (float4*)d_out);
}

// Round 8
// 152.896 us; speedup vs baseline: 1.1934x; 1.1074x over previous
//
#include <hip/hip_runtime.h>

// GCNConv + residual + ReLU, fp32 in/out — atomic-free binning + bf16 gather.
//   x  [N,64]  d_in[0]  float
//   W  [64,64] d_in[1]  float   (h = x @ W^T)
//   b  [64]    d_in[2]  float
//   ei [2,E]   d_in[3]  int32   (src = ei[0..E), dst = ei[E..2E))
// out [N,64] float
//
// h'[s][:] = bf16( dinv[s] * (x @ W^T)[s][:] )   (12.8 MB, gather-friendly)
// out[i]   = relu( dinv[i] * (h'[i] + sum_{s->i} h'[s]) + b + x[i] )
//
// R14 — ATOMIC-FREE FILL. Evidence across R6/R11/R12/R13: 800K returning
// global atomicAdds cost 35-56 us no matter the line layout, XCD locality,
// or read redundancy -> device returning-atomic throughput (~15-25 G/s) is
// itself the wall. This round eliminates them:
//   route: LDS-rank edges by dst&127 into per-(block,group) runs at FIXED
//          offsets (zero global atomics).
//   place: ONE block per group owns that group's 782 node counters in LDS;
//          ranks edges via LDS atomicAdd; bin stores single-writer by
//          construction; writes degrees to cur (replaces the memset).
// Prediction: fill path ~8-12 us total, dur ~125-140.

#define NN 100000
#define NE 800000
#define DD 64
#define CAP 32
#define ECHUNK 4096                 // edges per route block
#define NBLK 196                    // ceil(NE / ECHUNK)
#define NG 128                      // dst groups (g = dst & 127)
#define RCAP 96                     // per (block,group) run cap; mean 32, +11 sigma
#define GN 782                      // max nodes per group: ceil(NN/NG)
#define BMAX 8192                   // max edges per group map; mean 6250, +24 sigma

typedef unsigned int uint;
typedef unsigned short ushort;

__device__ __forceinline__ ushort f2bf(float f) {
    uint u = __float_as_uint(f);
    u += 0x7fffu + ((u >> 16) & 1u);   // round-to-nearest-even
    return (ushort)(u >> 16);
}
__device__ __forceinline__ float bflo(uint u) { return __uint_as_float(u << 16); }
__device__ __forceinline__ float bfhi(uint u) { return __uint_as_float(u & 0xffff0000u); }

// Pass 1: route edges into NG runs per block at fixed offsets. Coalesced
// edge read; LDS-atomic ranking only; no global atomics anywhere.
__global__ __launch_bounds__(256) void route_kernel(const int* __restrict__ ei,
                                                    int2* __restrict__ route,
                                                    int* __restrict__ counts) {
    __shared__ int lcnt[NG];
    int t = threadIdx.x;
    if (t < NG) lcnt[t] = 0;
    __syncthreads();

    int blk = blockIdx.x;
#pragma unroll
    for (int p = 0; p < 4; ++p) {
        int base = blk * ECHUNK + p * 1024 + t * 4;
        if (base < NE) {   // NE%4==0: full int4 safe
            int4 sv = *(const int4*)(ei + base);
            int4 dv = *(const int4*)(ei + NE + base);
            int s[4] = {sv.x, sv.y, sv.z, sv.w};
            int d[4] = {dv.x, dv.y, dv.z, dv.w};
#pragma unroll
            for (int j = 0; j < 4; ++j) {
                int g = d[j] & (NG - 1);
                int rk = atomicAdd(&lcnt[g], 1);    // LDS atomic
                if (rk < RCAP)
                    route[(size_t)(blk * NG + g) * RCAP + rk] =
                        make_int2(s[j], d[j]);
            }
        }
    }
    __syncthreads();
    if (t < NG) counts[blk * NG + t] = lcnt[t];
}

// Pass 2: block g (one per group) places all group-g edges. Node counters
// live in LDS (exclusive to this block); bin lines single-writer by
// construction. Epilogue writes degrees -> cur (no memset needed).
__global__ __launch_bounds__(256) void place_kernel(const int2* __restrict__ route,
                                                    const int* __restrict__ counts,
                                                    int* __restrict__ cur,
                                                    int* __restrict__ srcIdx) {
    __shared__ int    pref[256];     // inclusive scan of run counts (padded)
    __shared__ int    base_s[256];   // exclusive base per run
    __shared__ int    cnt_s[GN];     // per-node counters for this group
    __shared__ ushort blkmap[BMAX];  // flattened edge index -> run (blk)

    int g = blockIdx.x;
    int t = threadIdx.x;

    int c = 0;
    if (t < NBLK) {
        c = counts[t * NG + g];
        if (c > RCAP) c = RCAP;
    }
    pref[t] = c;
    __syncthreads();
#pragma unroll
    for (int off = 1; off < 256; off <<= 1) {   // Hillis-Steele inclusive scan
        int v = (t >= off) ? pref[t - off] : 0;
        __syncthreads();
        pref[t] += v;
        __syncthreads();
    }
    base_s[t] = pref[t] - c;
    for (int m = t; m < GN; m += 256) cnt_s[m] = 0;
    __syncthreads();

    int total = pref[255];
    if (total > BMAX) total = BMAX;

    if (t < NBLK) {   // fill blkmap: run t covers [base, base+c)
        int beg = base_s[t];
        for (int i = 0; i < c; ++i) {
            int idx = beg + i;
            if (idx < BMAX) blkmap[idx] = (ushort)t;
        }
    }
    __syncthreads();

    for (int j = t; j < total; j += 256) {
        int blk = blkmap[j];
        int2 e = route[(size_t)(blk * NG + g) * RCAP + (j - base_s[blk])];
        int m = e.y >> 7;                        // node index within group
        int cc = atomicAdd(&cnt_s[m], 1);        // LDS atomic
        if (cc < CAP) srcIdx[(e.y << 5) + cc] = e.x;
    }
    __syncthreads();

    for (int m = t; m * NG + g < NN; m += 256)   // degrees -> cur
        cur[m * NG + g] = cnt_s[m];
}

// Fallback single-pass fill (only if ws too small for route buffers).
__global__ __launch_bounds__(256) void fill_kernel(const int* __restrict__ ei,
                                                   int* __restrict__ cur,
                                                   int* __restrict__ srcIdx) {
    int base = (blockIdx.x * 256 + threadIdx.x) * 4;
    if (base >= NE) return;
    int4 sv = *(const int4*)(ei + base);
    int4 dv = *(const int4*)(ei + NE + base);
    int c0 = atomicAdd(&cur[dv.x], 1);
    int c1 = atomicAdd(&cur[dv.y], 1);
    int c2 = atomicAdd(&cur[dv.z], 1);
    int c3 = atomicAdd(&cur[dv.w], 1);
    if (c0 < CAP) srcIdx[(dv.x << 5) + c0] = sv.x;
    if (c1 < CAP) srcIdx[(dv.y << 5) + c1] = sv.y;
    if (c2 < CAP) srcIdx[(dv.z << 5) + c2] = sv.z;
    if (c3 < CAP) srcIdx[(dv.w << 5) + c3] = sv.w;
}

// linear: h' = bf16(rsqrt(deg+1) * (x @ W^T)).
// Block = 256 thr, tile 64 rows x 64 cols; thread = 4 contiguous rows x 4 cols.
// kq-loop capped at unroll 2 (full unroll spilled in R4: VGPR=256, scratch).
__global__ __launch_bounds__(256) void linear_kernel(const float4* __restrict__ x4g,
                                                     const float* __restrict__ W,
                                                     const int* __restrict__ deg,
                                                     ushort4* __restrict__ hq4) {
    __shared__ float4 wt4[64 * 16];   // 16 KB: wt4[k*16 + c4] = W^T[k][4c4..4c4+3]
    __shared__ float4 xs4[64 * 17];   // 17.4 KB, row-stride 17 float4
    int t = threadIdx.x;

    float* wt = (float*)wt4;
    for (int m = t; m < 4096; m += 256)            // wt[k*64+j] = W[j*64+k]
        wt[m] = W[(m & 63) * 64 + (m >> 6)];       // LDS write contiguous: clean

    int rowBase = blockIdx.x * 64;
    for (int m = t; m < 1024; m += 256) {
        int rl = m >> 4;
        xs4[rl * 17 + (m & 15)] = (rowBase + rl < NN)
            ? x4g[(size_t)rowBase * 16 + m]
            : make_float4(0.f, 0.f, 0.f, 0.f);
    }
    __syncthreads();

    int tc = t & 15;   // col-quad: cols tc*4..tc*4+3
    int tr = t >> 4;   // rows tr*4 .. tr*4+3
    float4 acc[4];
#pragma unroll
    for (int i = 0; i < 4; ++i) acc[i] = make_float4(0.f, 0.f, 0.f, 0.f);

#pragma unroll 2
    for (int kq = 0; kq < 16; ++kq) {
        float4 w0 = wt4[(kq * 4 + 0) * 16 + tc];
        float4 w1 = wt4[(kq * 4 + 1) * 16 + tc];
        float4 w2 = wt4[(kq * 4 + 2) * 16 + tc];
        float4 w3 = wt4[(kq * 4 + 3) * 16 + tc];
#pragma unroll
        for (int i = 0; i < 4; ++i) {
            float4 xv = xs4[(tr * 4 + i) * 17 + kq];
            acc[i].x += xv.x * w0.x + xv.y * w1.x + xv.z * w2.x + xv.w * w3.x;
            acc[i].y += xv.x * w0.y + xv.y * w1.y + xv.z * w2.y + xv.w * w3.y;
            acc[i].z += xv.x * w0.z + xv.y * w1.z + xv.z * w2.z + xv.w * w3.z;
            acc[i].w += xv.x * w0.w + xv.y * w1.w + xv.z * w2.w + xv.w * w3.w;
        }
    }

#pragma unroll
    for (int i = 0; i < 4; ++i) {
        int g = rowBase + tr * 4 + i;
        if (g < NN) {
            float sc = rsqrtf((float)deg[g] + 1.0f);
            ushort4 o;
            o.x = f2bf(acc[i].x * sc); o.y = f2bf(acc[i].y * sc);
            o.z = f2bf(acc[i].z * sc); o.w = f2bf(acc[i].w * sc);
            hq4[(size_t)g * 16 + tc] = o;
        }
    }
}

// gather: 8 lanes per node, lane covers 8 columns (one uint4 = 8 bf16 per load).
// Bin region is node-major: slots node*32 .. node*32+deg-1.
// Lane l prefetches bin slots 4l..4l+3 as ONE int4 (8 lanes cover the whole
// 128B bin, coalesced). Edge indices __shfl-broadcast; each 8-edge group
// issues up to 8 independent exec-predicated hq row loads (zero-init, bf
// decode of 0 is +0.0f). Self-loop, bias, residual, ReLU fused.
__global__ __launch_bounds__(256) void gather_kernel(const int* __restrict__ srcIdx,
                                                     const int* __restrict__ deg,
                                                     const uint4* __restrict__ hq4,
                                                     const float4* __restrict__ x4,
                                                     const float* __restrict__ b,
                                                     float4* __restrict__ out4) {
    int t = blockIdx.x * blockDim.x + threadIdx.x;
    int node = t >> 3;        // 32 nodes per block
    int l = t & 7;            // lane covers columns l*8 .. l*8+7
    if (node >= NN) return;

    int dg = deg[node];
    float di = rsqrtf((float)dg + 1.0f);
    if (dg > CAP) dg = CAP;   // astronomically unlikely; avoids unwritten slots

    // All independent loads up front: self row, my 4 bin slots, residual x.
    uint4 vs = hq4[(size_t)node * 8 + l];                      // self (pre-scaled)
    int4  u  = ((const int4*)srcIdx)[node * 8 + l];            // bin slots 4l..4l+3
    float4 xa = x4[(size_t)node * 16 + l * 2];
    float4 xb = x4[(size_t)node * 16 + l * 2 + 1];

    float acc[8];
    acc[0] = bflo(vs.x); acc[1] = bfhi(vs.x);
    acc[2] = bflo(vs.y); acc[3] = bfhi(vs.y);
    acc[4] = bflo(vs.z); acc[5] = bfhi(vs.z);
    acc[6] = bflo(vs.w); acc[7] = bfhi(vs.w);

    int base = (threadIdx.x & 63) & ~7;   // wave-local lane 0 of this node's group

#define ACC8(v)                                        \
    acc[0] += bflo((v).x); acc[1] += bfhi((v).x);      \
    acc[2] += bflo((v).y); acc[3] += bfhi((v).y);      \
    acc[4] += bflo((v).z); acc[5] += bfhi((v).z);      \
    acc[6] += bflo((v).w); acc[7] += bfhi((v).w);

#define GROUP(GI)                                                              \
    {                                                                          \
        int la = base + 2 * (GI), lb = la + 1, eb = (GI) * 8;                  \
        int s0 = __shfl(u.x, la, 64), s1 = __shfl(u.y, la, 64);                \
        int s2 = __shfl(u.z, la, 64), s3 = __shfl(u.w, la, 64);                \
        int s4 = __shfl(u.x, lb, 64), s5 = __shfl(u.y, lb, 64);                \
        int s6 = __shfl(u.z, lb, 64), s7 = __shfl(u.w, lb, 64);                \
        uint4 z = make_uint4(0u, 0u, 0u, 0u);                                  \
        uint4 v0 = z, v1 = z, v2 = z, v3 = z, v4 = z, v5 = z, v6 = z, v7 = z;  \
        if (eb + 0 < dg) v0 = hq4[(size_t)s0 * 8 + l];                         \
        if (eb + 1 < dg) v1 = hq4[(size_t)s1 * 8 + l];                         \
        if (eb + 2 < dg) v2 = hq4[(size_t)s2 * 8 + l];                         \
        if (eb + 3 < dg) v3 = hq4[(size_t)s3 * 8 + l];                         \
        if (eb + 4 < dg) v4 = hq4[(size_t)s4 * 8 + l];                         \
        if (eb + 5 < dg) v5 = hq4[(size_t)s5 * 8 + l];                         \
        if (eb + 6 < dg) v6 = hq4[(size_t)s6 * 8 + l];                         \
        if (eb + 7 < dg) v7 = hq4[(size_t)s7 * 8 + l];                         \
        ACC8(v0); ACC8(v1); ACC8(v2); ACC8(v3);                                \
        ACC8(v4); ACC8(v5); ACC8(v6); ACC8(v7);                                \
    }

    GROUP(0)
    if (dg > 8)  GROUP(1)
    if (dg > 16) GROUP(2)
    if (dg > 24) GROUP(3)

#undef GROUP
#undef ACC8

    float4 oa, ob;
    int cb = l * 8;
    oa.x = fmaxf(di * acc[0] + b[cb + 0] + xa.x, 0.f);
    oa.y = fmaxf(di * acc[1] + b[cb + 1] + xa.y, 0.f);
    oa.z = fmaxf(di * acc[2] + b[cb + 2] + xa.z, 0.f);
    oa.w = fmaxf(di * acc[3] + b[cb + 3] + xa.w, 0.f);
    ob.x = fmaxf(di * acc[4] + b[cb + 4] + xb.x, 0.f);
    ob.y = fmaxf(di * acc[5] + b[cb + 5] + xb.y, 0.f);
    ob.z = fmaxf(di * acc[6] + b[cb + 6] + xb.z, 0.f);
    ob.w = fmaxf(di * acc[7] + b[cb + 7] + xb.w, 0.f);
    out4[(size_t)node * 16 + l * 2]     = oa;
    out4[(size_t)node * 16 + l * 2 + 1] = ob;
}

extern "C" void kernel_launch(void* const* d_in, const int* in_sizes, int n_in,
                              void* d_out, int out_size, void* d_ws, size_t ws_size,
                              hipStream_t stream) {
    const float* x = (const float*)d_in[0];
    const float* W = (const float*)d_in[1];
    const float* b = (const float*)d_in[2];
    const int* ei = (const int*)d_in[3];

    char* ws = (char*)d_ws;
    int*    cur    = (int*)(ws + 0);           //    400,000 B (doubles as deg)
    int*    srcIdx = (int*)(ws + 400000);      // 12,800,000 B (node-major 32-slot bins)
    ushort* hq     = (ushort*)(ws + 13200000); // 12,800,000 B
    int2*   route  = (int2*)(ws + 26000000);   // 19,267,584 B (NBLK*NG runs of RCAP)
    int*    counts = (int*)(ws + 45267584);    //    100,352 B [blk][NG]
    const size_t WS_NEED = 45367936;

    if (ws_size >= WS_NEED) {
        route_kernel<<<NBLK, 256, 0, stream>>>(ei, route, counts);
        place_kernel<<<NG, 256, 0, stream>>>(route, counts, cur, srcIdx);
    } else {
        hipMemsetAsync(cur, 0, NN * sizeof(int), stream);
        fill_kernel<<<(NE / 4 + 255) / 256, 256, 0, stream>>>(ei, cur, srcIdx);
    }
    linear_kernel<<<(NN + 63) / 64, 256, 0, stream>>>((const float4*)x, W, cur,
                                                      (ushort4*)hq);
    gather_kernel<<<NN / 32, 256, 0, stream>>>(srcIdx, cur, (const uint4*)hq,
                                               (const float4*)x, b, (float4*)d_out);
}